// Round 10
// baseline (953.442 us; speedup 1.0000x reference)
//
#include <hip/hip_runtime.h>

// CrossViTPointFusion: N=262144 pts, B=16 segs, C=256, H=8, Dh=32.
// out = x_a @ Wo + bias[seg]; bias = bo + gamma*(cls_proj@Wo) (distributivity).
// Attention folded: logits = x_b . Kq[seg]; S = sum p*x_b; softmax shift-invariance => m=0 exact.
// Round 10: BARRIER-FREE wave-private GEMM. Each wave owns a disjoint 32-row stripe x 256 cols
// (acc 8 x f32x16), stages its own A-chunks (32 rows x 32 k) into a private 2KB LDS slot,
// synced only by per-wave lgkmcnt (DS ops in-order per wave). B block-shared in LDS (read-only
// after one prologue barrier). Depth-2 chunk register prefetch. nt stores, gamma==0 -> bo path.

#define NPTS 262144
#define NSEG 16
#define CDIM 256
#define HNUM 8
#define DH   32
#define NB   2048      // blocks for segsum/stats

#define GEMM_BLOCKS 256

using bf16x8 = __attribute__((ext_vector_type(8))) __bf16;
using f32x16 = __attribute__((ext_vector_type(16))) float;

__device__ __forceinline__ unsigned short f2bf(float f) {
  unsigned int u = __float_as_uint(f);
  unsigned int r = u + 0x7FFFu + ((u >> 16) & 1u);   // RNE, inputs finite
  return (unsigned short)(r >> 16);
}

// offsets: reference declares int64 but JAX without x64 yields int32. Sniff word 1.
__device__ __forceinline__ bool off_is64(const int* o) { return o[1] == 0; }
__device__ __forceinline__ long long off_at(const int* o, int i, bool is64) {
  return is64 ? ((const long long*)o)[i] : (long long)o[i];
}
__device__ __forceinline__ int seg_of(long long row, const int* o, bool is64) {
  int s = 0;
  while (s < NSEG - 1 && row >= off_at(o, s, is64)) ++s;
  return s;
}

// DPP rotate-add. CTRL: 0xB1 quad xor1, 0x4E quad xor2, 0x124 row_ror:4, 0x128 row_ror:8.
template <int CTRL>
__device__ __forceinline__ float dpp_add(float x) {
  int m = __builtin_amdgcn_update_dpp(0, __float_as_int(x), CTRL, 0xF, 0xF, true);
  return x + __int_as_float(m);
}

__device__ __forceinline__ void allred8(float lp[8]) {
  #pragma unroll
  for (int h = 0; h < 8; ++h) {
    float s = lp[h];
    s = dpp_add<0xB1>(s);
    s = dpp_add<0x4E>(s);
    s = dpp_add<0x124>(s);
    s = dpp_add<0x128>(s);
    s += __shfl_xor(s, 16, 64);
    s += __shfl_xor(s, 32, 64);
    lp[h] = s;
  }
}

// ---------------- K1: Wo^T bf16 (blocks 0..255) + per-segment column sums of x_a ----------------
__global__ __launch_bounds__(256) void k_wotseg(const float* __restrict__ Wo,
                                                unsigned short* __restrict__ wotp,
                                                const float* __restrict__ xa,
                                                const int* __restrict__ off,
                                                float* __restrict__ Apart,
                                                int* __restrict__ taga,
                                                float* __restrict__ cls_atomic,
                                                const float* __restrict__ gamma,
                                                int use_slots) {
  if (blockIdx.x < 256) {
    const int o = blockIdx.x * 256 + threadIdx.x;   // 65536; o = k*256+n (coalesced read)
    const int k = o >> 8, n = o & 255;
    wotp[n * CDIM + k] = f2bf(Wo[o]);
    return;
  }
  if (*gamma == 0.0f) return;     // attention path contributes gamma * (...) == 0 exactly
  const int bid = blockIdx.x - 256;
  const bool is64 = off_is64(off);
  const int t = threadIdx.x, lane = t & 63, w = t >> 6;
  const long long r0b = (long long)bid * 128;
  const int sg0 = seg_of(r0b, off, is64), sg1 = seg_of(r0b + 127, off, is64);
  const long long rw0 = r0b + (long long)w * 32;
  __shared__ float red[4][256];

  if (use_slots && sg0 == sg1) {
    float acc[4] = {0.f, 0.f, 0.f, 0.f};
    for (int r = 0; r < 32; ++r) {
      float4 xv = *(const float4*)&xa[(rw0 + r) * CDIM + lane * 4];
      acc[0] += xv.x; acc[1] += xv.y; acc[2] += xv.z; acc[3] += xv.w;
    }
    *(float4*)&red[w][lane * 4] = make_float4(acc[0], acc[1], acc[2], acc[3]);
    __syncthreads();
    Apart[bid * 256 + t] = red[0][t] + red[1][t] + red[2][t] + red[3][t];
    if (t == 0) taga[bid] = sg0;
  } else {
    int sg = seg_of(rw0, off, is64);
    long long segend = off_at(off, sg, is64);
    float acc[4] = {0.f, 0.f, 0.f, 0.f};
    for (int r = 0; r < 32; ++r) {
      long long row = rw0 + r;
      if (row >= segend) {
        #pragma unroll
        for (int i = 0; i < 4; ++i) { atomicAdd(&cls_atomic[sg * CDIM + lane * 4 + i], acc[i]); acc[i] = 0.f; }
        sg = seg_of(row, off, is64);
        segend = off_at(off, sg, is64);
      }
      float4 xv = *(const float4*)&xa[row * CDIM + lane * 4];
      acc[0] += xv.x; acc[1] += xv.y; acc[2] += xv.z; acc[3] += xv.w;
    }
    #pragma unroll
    for (int i = 0; i < 4; ++i) atomicAdd(&cls_atomic[sg * CDIM + lane * 4 + i], acc[i]);
    if (use_slots) {
      Apart[bid * 256 + t] = 0.f;
      if (t == 0) taga[bid] = -1;
    }
  }
}

// ---------------- K2: fused cls-reduce + q + Kq (16 blocks) ----------------
__global__ __launch_bounds__(256) void k_prep(const float* __restrict__ Apart,
                                              const int* __restrict__ taga,
                                              const float* __restrict__ cls_atomic,
                                              const int* __restrict__ off,
                                              const float* __restrict__ Wq,
                                              const float* __restrict__ Wk,
                                              float* __restrict__ Kq,
                                              const float* __restrict__ gamma,
                                              int nb) {
  if (*gamma == 0.0f) return;
  const int b = blockIdx.x, t = threadIdx.x;
  const bool is64 = off_is64(off);
  __shared__ float cls[256], qv[256];
  long long lo = b ? off_at(off, b - 1, is64) : 0;
  long long hi = off_at(off, b, is64);
  float s = cls_atomic[b * CDIM + t];
  if (nb > 0) {
    int wlo = (int)(lo / 128); if (wlo < 0) wlo = 0;
    int whi = (int)((hi + 127) / 128); if (whi > nb) whi = nb;
    for (int w = wlo; w < whi; ++w)
      if (taga[w] == b) s += Apart[w * 256 + t];
  }
  cls[t] = s;
  __syncthreads();
  long long cnt = hi - lo; if (cnt < 1) cnt = 1;
  float inv = 1.0f / (float)cnt;
  float qs = 0.f;
  for (int c = 0; c < CDIM; ++c) qs += cls[c] * Wq[c * CDIM + t];
  qv[t] = qs * inv;
  __syncthreads();
  const float scale = 0.17677669529663687f;
  #pragma unroll
  for (int h = 0; h < HNUM; ++h) {
    float kk = 0.f;
    #pragma unroll 8
    for (int d = 0; d < DH; ++d) kk += Wk[t * CDIM + h * DH + d] * qv[h * DH + d];
    Kq[(b * HNUM + h) * CDIM + t] = kk * scale;
  }
}

// ---------------- K3: fused stats pass over x_b -> per-block slots ----------------
__global__ __launch_bounds__(256) void k_stats(const float* __restrict__ xb,
                                               const int* __restrict__ off,
                                               const float* __restrict__ Kq,
                                               float* __restrict__ Spart,
                                               float* __restrict__ Dpart,
                                               int* __restrict__ tags,
                                               float* __restrict__ S_atomic,
                                               float* __restrict__ denom_atomic,
                                               const float* __restrict__ gamma,
                                               int use_slots) {
  if (*gamma == 0.0f) return;
  const bool is64 = off_is64(off);
  const int t = threadIdx.x, lane = t & 63, w = t >> 6;
  const long long r0b = (long long)blockIdx.x * 128;
  const int sg0 = seg_of(r0b, off, is64), sg1 = seg_of(r0b + 127, off, is64);
  const long long rw0 = r0b + (long long)w * 32;
  __shared__ float red[4][2048];
  __shared__ float dred[4][8];

  if (use_slots && sg0 == sg1) {
    float kq[8][4];
    #pragma unroll
    for (int h = 0; h < 8; ++h) {
      float4 v = *(const float4*)&Kq[(sg0 * 8 + h) * CDIM + lane * 4];
      kq[h][0] = v.x; kq[h][1] = v.y; kq[h][2] = v.z; kq[h][3] = v.w;
    }
    float sacc[8][4]; float dacc[8];
    #pragma unroll
    for (int h = 0; h < 8; ++h) { dacc[h] = 0.f; sacc[h][0]=sacc[h][1]=sacc[h][2]=sacc[h][3]=0.f; }

    #pragma unroll 2
    for (int r = 0; r < 32; ++r) {
      float4 xv = *(const float4*)&xb[(rw0 + r) * CDIM + lane * 4];
      float lp[8];
      #pragma unroll
      for (int h = 0; h < 8; ++h)
        lp[h] = xv.x*kq[h][0] + xv.y*kq[h][1] + xv.z*kq[h][2] + xv.w*kq[h][3];
      allred8(lp);
      #pragma unroll
      for (int h = 0; h < 8; ++h) {
        float p = __expf(lp[h]);
        dacc[h] += p;
        sacc[h][0] += p*xv.x; sacc[h][1] += p*xv.y; sacc[h][2] += p*xv.z; sacc[h][3] += p*xv.w;
      }
    }
    #pragma unroll
    for (int h = 0; h < 8; ++h)
      *(float4*)&red[w][h * 256 + lane * 4] = make_float4(sacc[h][0], sacc[h][1], sacc[h][2], sacc[h][3]);
    if (lane == 0) {
      #pragma unroll
      for (int h = 0; h < 8; ++h) dred[w][h] = dacc[h];
    }
    __syncthreads();
    #pragma unroll
    for (int k = 0; k < 8; ++k) {
      int e = k * 256 + t;
      Spart[(long long)blockIdx.x * 2048 + e] = red[0][e] + red[1][e] + red[2][e] + red[3][e];
    }
    if (t < 8) Dpart[blockIdx.x * 8 + t] = dred[0][t] + dred[1][t] + dred[2][t] + dred[3][t];
    if (t == 0) tags[blockIdx.x] = sg0;
  } else {
    int sg = seg_of(rw0, off, is64);
    long long segend = off_at(off, sg, is64);
    float kq[8][4];
    #pragma unroll
    for (int h = 0; h < 8; ++h) {
      float4 v = *(const float4*)&Kq[(sg * 8 + h) * CDIM + lane * 4];
      kq[h][0] = v.x; kq[h][1] = v.y; kq[h][2] = v.z; kq[h][3] = v.w;
    }
    float sacc[8][4]; float dacc[8];
    #pragma unroll
    for (int h = 0; h < 8; ++h) { dacc[h] = 0.f; sacc[h][0]=sacc[h][1]=sacc[h][2]=sacc[h][3]=0.f; }
    for (int r = 0; r < 32; ++r) {
      long long row = rw0 + r;
      if (row >= segend) {
        #pragma unroll
        for (int h = 0; h < 8; ++h) {
          #pragma unroll
          for (int i = 0; i < 4; ++i) { atomicAdd(&S_atomic[(sg*8+h)*CDIM + lane*4 + i], sacc[h][i]); sacc[h][i]=0.f; }
          if (lane == 0) atomicAdd(&denom_atomic[sg*8+h], dacc[h]);
          dacc[h] = 0.f;
        }
        sg = seg_of(row, off, is64);
        segend = off_at(off, sg, is64);
        #pragma unroll
        for (int h = 0; h < 8; ++h) {
          float4 v = *(const float4*)&Kq[(sg * 8 + h) * CDIM + lane * 4];
          kq[h][0] = v.x; kq[h][1] = v.y; kq[h][2] = v.z; kq[h][3] = v.w;
        }
      }
      float4 xv = *(const float4*)&xb[row * CDIM + lane * 4];
      float lp[8];
      #pragma unroll
      for (int h = 0; h < 8; ++h)
        lp[h] = xv.x*kq[h][0] + xv.y*kq[h][1] + xv.z*kq[h][2] + xv.w*kq[h][3];
      allred8(lp);
      #pragma unroll
      for (int h = 0; h < 8; ++h) {
        float p = __expf(lp[h]);
        dacc[h] += p;
        sacc[h][0] += p*xv.x; sacc[h][1] += p*xv.y; sacc[h][2] += p*xv.z; sacc[h][3] += p*xv.w;
      }
    }
    #pragma unroll
    for (int h = 0; h < 8; ++h) {
      #pragma unroll
      for (int i = 0; i < 4; ++i) atomicAdd(&S_atomic[(sg*8+h)*CDIM + lane*4 + i], sacc[h][i]);
      if (lane == 0) atomicAdd(&denom_atomic[sg*8+h], dacc[h]);
    }
    if (use_slots) {
      #pragma unroll
      for (int k = 0; k < 8; ++k) Spart[(long long)blockIdx.x * 2048 + k * 256 + t] = 0.f;
      if (t < 8) Dpart[blockIdx.x * 8 + t] = 0.f;
      if (t == 0) tags[blockIdx.x] = -1;
    }
  }
}

// ---------------- K4: slot-reduce + out_cls + MLP chain + biasv (16 blocks) ----------------
__global__ __launch_bounds__(256) void k_post(const float* __restrict__ Spart,
                                              const float* __restrict__ Dpart,
                                              const int* __restrict__ tags,
                                              const float* __restrict__ S_atomic,
                                              const float* __restrict__ denom_atomic,
                                              const int* __restrict__ off,
                                              const float* __restrict__ Wv,
                                              const float* __restrict__ Wp, const float* __restrict__ bp,
                                              const float* __restrict__ Wr1, const float* __restrict__ br1,
                                              const float* __restrict__ Wr2, const float* __restrict__ br2,
                                              const float* __restrict__ gamma,
                                              const float* __restrict__ Wo, const float* __restrict__ bo,
                                              float* __restrict__ biasv,
                                              int nb) {
  const int b = blockIdx.x, t = threadIdx.x;
  const float g = *gamma;
  if (g == 0.0f) return;          // k_gemm sources bo directly when gamma==0
  const bool is64 = off_is64(off);
  __shared__ float sb[8][256];
  __shared__ float db[8];
  __shared__ float v0[256], v1[256];
  long long lo = b ? off_at(off, b - 1, is64) : 0;
  long long hi = off_at(off, b, is64);
  int wlo = (int)(lo / 128); if (wlo < 0) wlo = 0;
  int whi = (int)((hi + 127) / 128); if (whi > nb) whi = nb;
  #pragma unroll
  for (int k = 0; k < 8; ++k) {
    const int e = k * 256 + t;
    float s = S_atomic[b * 2048 + e];
    for (int w = wlo; w < whi; ++w)
      if (tags[w] == b) s += Spart[(long long)w * 2048 + e];
    sb[k][t] = s;
  }
  if (t < 8) {
    float d = denom_atomic[b * 8 + t];
    for (int w = wlo; w < whi; ++w)
      if (tags[w] == b) d += Dpart[w * 8 + t];
    db[t] = d;
  }
  __syncthreads();
  const int h = t >> 5;
  float oc = 0.f;
  for (int c = 0; c < CDIM; ++c) oc += Wv[c * CDIM + t] * sb[h][c];
  oc /= db[h];
  v0[t] = oc;
  __syncthreads();
  float a = bp[t];
  for (int c = 0; c < CDIM; ++c) a += v0[c] * Wp[c * CDIM + t];
  v1[t] = a;
  __syncthreads();
  float r1 = br1[t];
  for (int c = 0; c < CDIM; ++c) r1 += v1[c] * Wr1[c * CDIM + t];
  r1 = fmaxf(r1, 0.f);
  v0[t] = r1;
  __syncthreads();
  float r2 = br2[t];
  for (int c = 0; c < CDIM; ++c) r2 += v0[c] * Wr2[c * CDIM + t];
  v1[t] = r2;
  __syncthreads();
  float acc = 0.f;
  for (int c = 0; c < CDIM; ++c) acc += v1[c] * Wo[c * CDIM + t];
  biasv[b * CDIM + t] = bo[t] + g * acc;
}

// ---------------- K5: out = xa @ Wo + bias[seg]  (barrier-free wave-private) ----------------
// 256 blocks x 512 thr (8 waves). Wave owns rows [w*32, w*32+32) of each 256-row block-tile,
// all 256 cols (acc = 8 x f32x16). A chunks (32 rows x 32 k) staged into a PRIVATE 2KB LDS
// slot; per-wave lgkmcnt ordering only (DS ops in-order per wave). Depth-2 chunk prefetch.
// B (wot bf16, 128 KB) block-shared, read-only after single prologue barrier. nt stores.

// one step: s in [0,32): iter = s>>3 (row-tile), chunk = s&7 (32-k slice)
#define GSTEP(G, S)                                                                   \
  {                                                                                   \
    _Pragma("unroll")                                                                 \
    for (int i = 0; i < 4; ++i) {                                                     \
      uint2 wv;                                                                       \
      wv.x = (unsigned int)f2bf(G[i].x) | ((unsigned int)f2bf(G[i].y) << 16);         \
      wv.y = (unsigned int)f2bf(G[i].z) | ((unsigned int)f2bf(G[i].w) << 16);         \
      *(uint2*)((char*)Aw + awsw[i]) = wv;                                            \
    }                                                                                 \
    {                                                                                 \
      const int sn = ((S) + 2 < 32) ? (S) + 2 : (S);                                  \
      const float* pn = APTR(sn);                                                     \
      _Pragma("unroll")                                                               \
      for (int i = 0; i < 4; ++i) G[i] = *(const float4*)(pn + i * 8 * CDIM);         \
    }                                                                                 \
    asm volatile("s_waitcnt lgkmcnt(0)" ::: "memory");                                \
    const int cb = ((S) & 7) * 64;                                                    \
    _Pragma("unroll")                                                                 \
    for (int ks = 0; ks < 2; ++ks) {                                                  \
      const bf16x8 a = *(const bf16x8*)((const char*)Aw + ars0 +                      \
                         ((ks * 32 + hib) ^ aswz));                                   \
      _Pragma("unroll")                                                               \
      for (int j = 0; j < 8; ++j) {                                                   \
        const int nb = j * 32 + ra;                                                   \
        const bf16x8 b = *(const bf16x8*)((const char*)Bs + nb * 512 +                \
                           ((cb + ks * 32 + hib) ^ ((nb & 31) << 4)));                \
        acc[j] = __builtin_amdgcn_mfma_f32_32x32x16_bf16(a, b, acc[j], 0, 0, 0);      \
      }                                                                               \
    }                                                                                 \
    if (((S) & 7) == 7) {                                                             \
      const long long r0 = (bid + (long long)((S) >> 3) * GEMM_BLOCKS) * 256 + w * 32;\
      const int sgw = seg_of(r0, off, is64);                                          \
      const bool uni = g0 || (sgw == seg_of(r0 + 31, off, is64));                     \
      _Pragma("unroll")                                                               \
      for (int j = 0; j < 8; ++j) {                                                   \
        const int col = j * 32 + ra;                                                  \
        const float bvu = g0 ? bo[col] : bias[sgw * CDIM + col];                      \
        _Pragma("unroll")                                                             \
        for (int reg = 0; reg < 16; ++reg) {                                          \
          const int rin = 4 * (lane >> 5) + (reg & 3) + 8 * (reg >> 2);               \
          const long long grow = r0 + rin;                                            \
          float bb = uni ? bvu : bias[seg_of(grow, off, is64) * CDIM + col];          \
          __builtin_nontemporal_store(acc[j][reg] + bb, &out[grow * CDIM + col]);     \
        }                                                                             \
        _Pragma("unroll")                                                             \
        for (int rr = 0; rr < 16; ++rr) acc[j][rr] = 0.0f;                            \
      }                                                                               \
    }                                                                                 \
  }

#define APTR(S) (xa + ((bid + (long long)((S) >> 3) * GEMM_BLOCKS) * 256 + w * 32 + srow) * (long long)CDIM + ((S) & 7) * 32 + sc * 4)

__global__ __launch_bounds__(512, 2) void k_gemm(const float* __restrict__ xa,
                                                 const unsigned short* __restrict__ wot,
                                                 const float* __restrict__ bias,
                                                 const float* __restrict__ bo,
                                                 const float* __restrict__ gamma,
                                                 const int* __restrict__ off,
                                                 float* __restrict__ out) {
  extern __shared__ char smem[];
  unsigned short* Bs = (unsigned short*)smem;                       // 131072 B, block-shared
  const int t = threadIdx.x, lane = t & 63, w = t >> 6;
  unsigned short* Aw = (unsigned short*)(smem + 131072 + w * 2048); // per-wave 2 KB

  const bool is64 = off_is64(off);
  const bool g0 = (*gamma == 0.0f);
  const long long bid = blockIdx.x;

  // A staging coords: chunk = 32 rows x 32 k; lane stages rows srow+8i, float4 sc
  const int srow = lane >> 3;     // 0..7
  const int sc   = lane & 7;      // 16B chunk within 32-k row (8 x 16B = 128B f32)
  int awsw[4];
  #pragma unroll
  for (int i = 0; i < 4; ++i) {
    const int r = srow + 8 * i;
    awsw[i] = r * 64 + ((sc * 8) ^ ((r & 3) << 4));   // bf16 row = 64B, 16B-granule XOR swizzle
  }
  // MFMA read coords
  const int ra   = lane & 31;
  const int hib  = (lane >> 5) * 16;   // byte offset selecting 8-elem half of 16-k
  const int ars0 = ra * 64;
  const int aswz = (ra & 3) << 4;

  // prologue: issue chunk loads for s=0,1 (in flight during B staging)
  float4 g0v[4], g1v[4];
  {
    const float* p0 = APTR(0);
    const float* p1 = APTR(1);
    #pragma unroll
    for (int i = 0; i < 4; ++i) {
      g0v[i] = *(const float4*)(p0 + i * 8 * CDIM);
      g1v[i] = *(const float4*)(p1 + i * 8 * CDIM);
    }
  }

  // stage B once (the ONLY block barrier)
  #pragma unroll
  for (int pp = 0; pp < 16; ++pp) {
    int q = t + pp * 512;
    int n = q >> 5, c = q & 31;
    uint4 u = *(const uint4*)(wot + n * CDIM + c * 8);
    int d = n * 512 + ((c * 16) ^ ((n & 31) << 4));
    *(uint4*)((char*)Bs + d) = u;
  }
  __syncthreads();

  f32x16 acc[8] = {};

  #pragma unroll 1
  for (int s2 = 0; s2 < 32; s2 += 2) {
    GSTEP(g0v, s2);
    GSTEP(g1v, s2 + 1);
  }
}

extern "C" void kernel_launch(void* const* d_in, const int* in_sizes, int n_in,
                              void* d_out, int out_size, void* d_ws, size_t ws_size,
                              hipStream_t stream) {
  const float* xa    = (const float*)d_in[0];
  const float* xb    = (const float*)d_in[1];
  const int*   off   = (const int*)d_in[2];
  const float* Wq    = (const float*)d_in[3];
  const float* Wk    = (const float*)d_in[4];
  const float* Wv    = (const float*)d_in[5];
  const float* Wp    = (const float*)d_in[6];
  const float* bp    = (const float*)d_in[7];
  const float* Wr1   = (const float*)d_in[8];
  const float* br1   = (const float*)d_in[9];
  const float* Wr2   = (const float*)d_in[10];
  const float* br2   = (const float*)d_in[11];
  const float* gamma = (const float*)d_in[12];
  const float* Wo    = (const float*)d_in[13];
  const float* bo    = (const float*)d_in[14];
  float* out = (float*)d_out;

  float* ws = (float*)d_ws;
  float* S_atomic   = ws + 0;        // 32768
  float* cls_atomic = ws + 32768;    // 4096
  float* denom_at   = ws + 36864;    // 128   (zero region [0,36992))
  float* Kq         = ws + 69888;    // 32768
  float* biasv      = ws + 102656;   // 4096
  unsigned short* wot = (unsigned short*)(ws + 106752); // 65536 bf16 (32768 floats)
  int*   tags_s     = (int*)(ws + 139520);   // 2048
  int*   taga       = (int*)(ws + 141568);   // 2048
  float* Dpart      = ws + 143616;   // 16384
  float* Apart      = ws + 160000;   // 524288
  float* Spart      = ws + 684288;   // 4194304
  const size_t needed = (size_t)(684288 + 4194304) * 4;   // ~19.5 MB
  const int use_slots = (ws_size >= needed) ? 1 : 0;

  hipMemsetAsync(ws, 0, 36992 * sizeof(float), stream);

  k_wotseg<<<256 + NB, 256, 0, stream>>>(Wo, wot, xa, off, Apart, taga, cls_atomic, gamma, use_slots);
  k_prep  <<<16,  256, 0, stream>>>(Apart, taga, cls_atomic, off, Wq, Wk, Kq, gamma, use_slots ? NB : 0);
  k_stats <<<NB,  256, 0, stream>>>(xb, off, Kq, Spart, Dpart, tags_s, S_atomic, denom_at, gamma, use_slots);
  k_post  <<<16,  256, 0, stream>>>(Spart, Dpart, tags_s, S_atomic, denom_at, off, Wv, Wp, bp,
                                    Wr1, br1, Wr2, br2, gamma, Wo, bo, biasv, use_slots ? NB : 0);
  k_gemm  <<<GEMM_BLOCKS, 512, 147456, stream>>>(xa, wot, biasv, bo, gamma, off, out);
}

// Round 11
// 105.036 us; speedup vs baseline: 9.0773x; 9.0773x over previous
//
#include <hip/hip_runtime.h>

// CrossViTPointFusion: N=262144 pts, B=16 segs, C=256, H=8, Dh=32.
// out = x_a @ Wo + bias[seg]; bias = bo + gamma*(cls_proj@Wo) (distributivity).
// Attention folded: logits = x_b . Kq[seg]; S = sum p*x_b; softmax shift-invariance => m=0 exact.
// Round 11: REVERT to round-9 kernel (best: 104.7 us). Round-10's barrier-free variant
// falsified: nt partial-line writes without barrier-synced bursts -> RMW amplification
// (WRITE 10x, FETCH 4x). r9 = wot-staged LDS B, full-tile register prefetch, lgkm-only
// barriers, nt stores, bo-direct gamma==0 path. 6 dispatches.

#define NPTS 262144
#define NSEG 16
#define CDIM 256
#define HNUM 8
#define DH   32
#define NB   2048      // blocks for segsum/stats

#define GEMM_BLOCKS 256
#define GEMM_NT     4096     // 262144 / 64 rows per tile

using bf16x8 = __attribute__((ext_vector_type(8))) __bf16;
using f32x16 = __attribute__((ext_vector_type(16))) float;

__device__ __forceinline__ unsigned short f2bf(float f) {
  unsigned int u = __float_as_uint(f);
  unsigned int r = u + 0x7FFFu + ((u >> 16) & 1u);   // RNE, inputs finite
  return (unsigned short)(r >> 16);
}

// offsets: reference declares int64 but JAX without x64 yields int32. Sniff word 1.
__device__ __forceinline__ bool off_is64(const int* o) { return o[1] == 0; }
__device__ __forceinline__ long long off_at(const int* o, int i, bool is64) {
  return is64 ? ((const long long*)o)[i] : (long long)o[i];
}
__device__ __forceinline__ int seg_of(long long row, const int* o, bool is64) {
  int s = 0;
  while (s < NSEG - 1 && row >= off_at(o, s, is64)) ++s;
  return s;
}

// DPP rotate-add. CTRL: 0xB1 quad xor1, 0x4E quad xor2, 0x124 row_ror:4, 0x128 row_ror:8.
template <int CTRL>
__device__ __forceinline__ float dpp_add(float x) {
  int m = __builtin_amdgcn_update_dpp(0, __float_as_int(x), CTRL, 0xF, 0xF, true);
  return x + __int_as_float(m);
}

__device__ __forceinline__ void allred8(float lp[8]) {
  #pragma unroll
  for (int h = 0; h < 8; ++h) {
    float s = lp[h];
    s = dpp_add<0xB1>(s);
    s = dpp_add<0x4E>(s);
    s = dpp_add<0x124>(s);
    s = dpp_add<0x128>(s);
    s += __shfl_xor(s, 16, 64);
    s += __shfl_xor(s, 32, 64);
    lp[h] = s;
  }
}

// ---------------- K1: Wo^T bf16 (blocks 0..255) + per-segment column sums of x_a ----------------
__global__ __launch_bounds__(256) void k_wotseg(const float* __restrict__ Wo,
                                                unsigned short* __restrict__ wotp,
                                                const float* __restrict__ xa,
                                                const int* __restrict__ off,
                                                float* __restrict__ Apart,
                                                int* __restrict__ taga,
                                                float* __restrict__ cls_atomic,
                                                const float* __restrict__ gamma,
                                                int use_slots) {
  if (blockIdx.x < 256) {
    const int o = blockIdx.x * 256 + threadIdx.x;   // 65536; o = k*256+n (coalesced read)
    const int k = o >> 8, n = o & 255;
    wotp[n * CDIM + k] = f2bf(Wo[o]);
    return;
  }
  if (*gamma == 0.0f) return;     // attention path contributes gamma * (...) == 0 exactly
  const int bid = blockIdx.x - 256;
  const bool is64 = off_is64(off);
  const int t = threadIdx.x, lane = t & 63, w = t >> 6;
  const long long r0b = (long long)bid * 128;
  const int sg0 = seg_of(r0b, off, is64), sg1 = seg_of(r0b + 127, off, is64);
  const long long rw0 = r0b + (long long)w * 32;
  __shared__ float red[4][256];

  if (use_slots && sg0 == sg1) {
    float acc[4] = {0.f, 0.f, 0.f, 0.f};
    for (int r = 0; r < 32; ++r) {
      float4 xv = *(const float4*)&xa[(rw0 + r) * CDIM + lane * 4];
      acc[0] += xv.x; acc[1] += xv.y; acc[2] += xv.z; acc[3] += xv.w;
    }
    *(float4*)&red[w][lane * 4] = make_float4(acc[0], acc[1], acc[2], acc[3]);
    __syncthreads();
    Apart[bid * 256 + t] = red[0][t] + red[1][t] + red[2][t] + red[3][t];
    if (t == 0) taga[bid] = sg0;
  } else {
    int sg = seg_of(rw0, off, is64);
    long long segend = off_at(off, sg, is64);
    float acc[4] = {0.f, 0.f, 0.f, 0.f};
    for (int r = 0; r < 32; ++r) {
      long long row = rw0 + r;
      if (row >= segend) {
        #pragma unroll
        for (int i = 0; i < 4; ++i) { atomicAdd(&cls_atomic[sg * CDIM + lane * 4 + i], acc[i]); acc[i] = 0.f; }
        sg = seg_of(row, off, is64);
        segend = off_at(off, sg, is64);
      }
      float4 xv = *(const float4*)&xa[row * CDIM + lane * 4];
      acc[0] += xv.x; acc[1] += xv.y; acc[2] += xv.z; acc[3] += xv.w;
    }
    #pragma unroll
    for (int i = 0; i < 4; ++i) atomicAdd(&cls_atomic[sg * CDIM + lane * 4 + i], acc[i]);
    if (use_slots) {
      Apart[bid * 256 + t] = 0.f;
      if (t == 0) taga[bid] = -1;
    }
  }
}

// ---------------- K2: fused cls-reduce + q + Kq (16 blocks) ----------------
__global__ __launch_bounds__(256) void k_prep(const float* __restrict__ Apart,
                                              const int* __restrict__ taga,
                                              const float* __restrict__ cls_atomic,
                                              const int* __restrict__ off,
                                              const float* __restrict__ Wq,
                                              const float* __restrict__ Wk,
                                              float* __restrict__ Kq,
                                              const float* __restrict__ gamma,
                                              int nb) {
  if (*gamma == 0.0f) return;
  const int b = blockIdx.x, t = threadIdx.x;
  const bool is64 = off_is64(off);
  __shared__ float cls[256], qv[256];
  long long lo = b ? off_at(off, b - 1, is64) : 0;
  long long hi = off_at(off, b, is64);
  float s = cls_atomic[b * CDIM + t];
  if (nb > 0) {
    int wlo = (int)(lo / 128); if (wlo < 0) wlo = 0;
    int whi = (int)((hi + 127) / 128); if (whi > nb) whi = nb;
    for (int w = wlo; w < whi; ++w)
      if (taga[w] == b) s += Apart[w * 256 + t];
  }
  cls[t] = s;
  __syncthreads();
  long long cnt = hi - lo; if (cnt < 1) cnt = 1;
  float inv = 1.0f / (float)cnt;
  float qs = 0.f;
  for (int c = 0; c < CDIM; ++c) qs += cls[c] * Wq[c * CDIM + t];
  qv[t] = qs * inv;
  __syncthreads();
  const float scale = 0.17677669529663687f;
  #pragma unroll
  for (int h = 0; h < HNUM; ++h) {
    float kk = 0.f;
    #pragma unroll 8
    for (int d = 0; d < DH; ++d) kk += Wk[t * CDIM + h * DH + d] * qv[h * DH + d];
    Kq[(b * HNUM + h) * CDIM + t] = kk * scale;
  }
}

// ---------------- K3: fused stats pass over x_b -> per-block slots ----------------
__global__ __launch_bounds__(256) void k_stats(const float* __restrict__ xb,
                                               const int* __restrict__ off,
                                               const float* __restrict__ Kq,
                                               float* __restrict__ Spart,
                                               float* __restrict__ Dpart,
                                               int* __restrict__ tags,
                                               float* __restrict__ S_atomic,
                                               float* __restrict__ denom_atomic,
                                               const float* __restrict__ gamma,
                                               int use_slots) {
  if (*gamma == 0.0f) return;
  const bool is64 = off_is64(off);
  const int t = threadIdx.x, lane = t & 63, w = t >> 6;
  const long long r0b = (long long)blockIdx.x * 128;
  const int sg0 = seg_of(r0b, off, is64), sg1 = seg_of(r0b + 127, off, is64);
  const long long rw0 = r0b + (long long)w * 32;
  __shared__ float red[4][2048];
  __shared__ float dred[4][8];

  if (use_slots && sg0 == sg1) {
    float kq[8][4];
    #pragma unroll
    for (int h = 0; h < 8; ++h) {
      float4 v = *(const float4*)&Kq[(sg0 * 8 + h) * CDIM + lane * 4];
      kq[h][0] = v.x; kq[h][1] = v.y; kq[h][2] = v.z; kq[h][3] = v.w;
    }
    float sacc[8][4]; float dacc[8];
    #pragma unroll
    for (int h = 0; h < 8; ++h) { dacc[h] = 0.f; sacc[h][0]=sacc[h][1]=sacc[h][2]=sacc[h][3]=0.f; }

    #pragma unroll 2
    for (int r = 0; r < 32; ++r) {
      float4 xv = *(const float4*)&xb[(rw0 + r) * CDIM + lane * 4];
      float lp[8];
      #pragma unroll
      for (int h = 0; h < 8; ++h)
        lp[h] = xv.x*kq[h][0] + xv.y*kq[h][1] + xv.z*kq[h][2] + xv.w*kq[h][3];
      allred8(lp);
      #pragma unroll
      for (int h = 0; h < 8; ++h) {
        float p = __expf(lp[h]);
        dacc[h] += p;
        sacc[h][0] += p*xv.x; sacc[h][1] += p*xv.y; sacc[h][2] += p*xv.z; sacc[h][3] += p*xv.w;
      }
    }
    #pragma unroll
    for (int h = 0; h < 8; ++h)
      *(float4*)&red[w][h * 256 + lane * 4] = make_float4(sacc[h][0], sacc[h][1], sacc[h][2], sacc[h][3]);
    if (lane == 0) {
      #pragma unroll
      for (int h = 0; h < 8; ++h) dred[w][h] = dacc[h];
    }
    __syncthreads();
    #pragma unroll
    for (int k = 0; k < 8; ++k) {
      int e = k * 256 + t;
      Spart[(long long)blockIdx.x * 2048 + e] = red[0][e] + red[1][e] + red[2][e] + red[3][e];
    }
    if (t < 8) Dpart[blockIdx.x * 8 + t] = dred[0][t] + dred[1][t] + dred[2][t] + dred[3][t];
    if (t == 0) tags[blockIdx.x] = sg0;
  } else {
    int sg = seg_of(rw0, off, is64);
    long long segend = off_at(off, sg, is64);
    float kq[8][4];
    #pragma unroll
    for (int h = 0; h < 8; ++h) {
      float4 v = *(const float4*)&Kq[(sg * 8 + h) * CDIM + lane * 4];
      kq[h][0] = v.x; kq[h][1] = v.y; kq[h][2] = v.z; kq[h][3] = v.w;
    }
    float sacc[8][4]; float dacc[8];
    #pragma unroll
    for (int h = 0; h < 8; ++h) { dacc[h] = 0.f; sacc[h][0]=sacc[h][1]=sacc[h][2]=sacc[h][3]=0.f; }
    for (int r = 0; r < 32; ++r) {
      long long row = rw0 + r;
      if (row >= segend) {
        #pragma unroll
        for (int h = 0; h < 8; ++h) {
          #pragma unroll
          for (int i = 0; i < 4; ++i) { atomicAdd(&S_atomic[(sg*8+h)*CDIM + lane*4 + i], sacc[h][i]); sacc[h][i]=0.f; }
          if (lane == 0) atomicAdd(&denom_atomic[sg*8+h], dacc[h]);
          dacc[h] = 0.f;
        }
        sg = seg_of(row, off, is64);
        segend = off_at(off, sg, is64);
        #pragma unroll
        for (int h = 0; h < 8; ++h) {
          float4 v = *(const float4*)&Kq[(sg * 8 + h) * CDIM + lane * 4];
          kq[h][0] = v.x; kq[h][1] = v.y; kq[h][2] = v.z; kq[h][3] = v.w;
        }
      }
      float4 xv = *(const float4*)&xb[row * CDIM + lane * 4];
      float lp[8];
      #pragma unroll
      for (int h = 0; h < 8; ++h)
        lp[h] = xv.x*kq[h][0] + xv.y*kq[h][1] + xv.z*kq[h][2] + xv.w*kq[h][3];
      allred8(lp);
      #pragma unroll
      for (int h = 0; h < 8; ++h) {
        float p = __expf(lp[h]);
        dacc[h] += p;
        sacc[h][0] += p*xv.x; sacc[h][1] += p*xv.y; sacc[h][2] += p*xv.z; sacc[h][3] += p*xv.w;
      }
    }
    #pragma unroll
    for (int h = 0; h < 8; ++h) {
      #pragma unroll
      for (int i = 0; i < 4; ++i) atomicAdd(&S_atomic[(sg*8+h)*CDIM + lane*4 + i], sacc[h][i]);
      if (lane == 0) atomicAdd(&denom_atomic[sg*8+h], dacc[h]);
    }
    if (use_slots) {
      #pragma unroll
      for (int k = 0; k < 8; ++k) Spart[(long long)blockIdx.x * 2048 + k * 256 + t] = 0.f;
      if (t < 8) Dpart[blockIdx.x * 8 + t] = 0.f;
      if (t == 0) tags[blockIdx.x] = -1;
    }
  }
}

// ---------------- K4: slot-reduce + out_cls + MLP chain + biasv (16 blocks) ----------------
__global__ __launch_bounds__(256) void k_post(const float* __restrict__ Spart,
                                              const float* __restrict__ Dpart,
                                              const int* __restrict__ tags,
                                              const float* __restrict__ S_atomic,
                                              const float* __restrict__ denom_atomic,
                                              const int* __restrict__ off,
                                              const float* __restrict__ Wv,
                                              const float* __restrict__ Wp, const float* __restrict__ bp,
                                              const float* __restrict__ Wr1, const float* __restrict__ br1,
                                              const float* __restrict__ Wr2, const float* __restrict__ br2,
                                              const float* __restrict__ gamma,
                                              const float* __restrict__ Wo, const float* __restrict__ bo,
                                              float* __restrict__ biasv,
                                              int nb) {
  const int b = blockIdx.x, t = threadIdx.x;
  const float g = *gamma;
  if (g == 0.0f) return;          // k_gemm sources bo directly when gamma==0
  const bool is64 = off_is64(off);
  __shared__ float sb[8][256];
  __shared__ float db[8];
  __shared__ float v0[256], v1[256];
  long long lo = b ? off_at(off, b - 1, is64) : 0;
  long long hi = off_at(off, b, is64);
  int wlo = (int)(lo / 128); if (wlo < 0) wlo = 0;
  int whi = (int)((hi + 127) / 128); if (whi > nb) whi = nb;
  #pragma unroll
  for (int k = 0; k < 8; ++k) {
    const int e = k * 256 + t;
    float s = S_atomic[b * 2048 + e];
    for (int w = wlo; w < whi; ++w)
      if (tags[w] == b) s += Spart[(long long)w * 2048 + e];
    sb[k][t] = s;
  }
  if (t < 8) {
    float d = denom_atomic[b * 8 + t];
    for (int w = wlo; w < whi; ++w)
      if (tags[w] == b) d += Dpart[w * 8 + t];
    db[t] = d;
  }
  __syncthreads();
  const int h = t >> 5;
  float oc = 0.f;
  for (int c = 0; c < CDIM; ++c) oc += Wv[c * CDIM + t] * sb[h][c];
  oc /= db[h];
  v0[t] = oc;
  __syncthreads();
  float a = bp[t];
  for (int c = 0; c < CDIM; ++c) a += v0[c] * Wp[c * CDIM + t];
  v1[t] = a;
  __syncthreads();
  float r1 = br1[t];
  for (int c = 0; c < CDIM; ++c) r1 += v1[c] * Wr1[c * CDIM + t];
  r1 = fmaxf(r1, 0.f);
  v0[t] = r1;
  __syncthreads();
  float r2 = br2[t];
  for (int c = 0; c < CDIM; ++c) r2 += v0[c] * Wr2[c * CDIM + t];
  v1[t] = r2;
  __syncthreads();
  float acc = 0.f;
  for (int c = 0; c < CDIM; ++c) acc += v1[c] * Wo[c * CDIM + t];
  biasv[b * CDIM + t] = bo[t] + g * acc;
}

// ---------------- K5 helpers ----------------
__device__ __forceinline__ void gemm_mfma_step(const unsigned short* Abuf,
                                               const unsigned short* Bs,
                                               int rA, int hi16, int nB0, int nB1, int sbyte,
                                               f32x16& acc0, f32x16& acc1) {
  #pragma unroll
  for (int ks = 0; ks < 4; ++ks) {
    const bf16x8 a = *(const bf16x8*)((const char*)Abuf + rA * 128 +
                       ((ks * 32 + hi16) ^ ((rA & 7) << 4)));
    const bf16x8 b0 = *(const bf16x8*)((const char*)Bs + nB0 * 512 +
                       ((sbyte + ks * 32 + hi16) ^ ((nB0 & 31) << 4)));
    const bf16x8 b1 = *(const bf16x8*)((const char*)Bs + nB1 * 512 +
                       ((sbyte + ks * 32 + hi16) ^ ((nB1 & 31) << 4)));
    acc0 = __builtin_amdgcn_mfma_f32_32x32x16_bf16(a, b0, acc0, 0, 0, 0);
    acc1 = __builtin_amdgcn_mfma_f32_32x32x16_bf16(a, b1, acc1, 0, 0, 0);
  }
}

__device__ __forceinline__ void gemm_cvt_write(const float4& sa, const float4& sb,
                                               unsigned short* Abuf, int aws0, int aws1) {
  unsigned int u0 = (unsigned int)f2bf(sa.x) | ((unsigned int)f2bf(sa.y) << 16);
  unsigned int u1 = (unsigned int)f2bf(sa.z) | ((unsigned int)f2bf(sa.w) << 16);
  unsigned int u2 = (unsigned int)f2bf(sb.x) | ((unsigned int)f2bf(sb.y) << 16);
  unsigned int u3 = (unsigned int)f2bf(sb.z) | ((unsigned int)f2bf(sb.w) << 16);
  uint2 w0; w0.x = u0; w0.y = u1;
  uint2 w1; w1.x = u2; w1.y = u3;
  *(uint2*)((char*)Abuf + aws0) = w0;
  *(uint2*)((char*)Abuf + aws1) = w1;
}

#define GEMM_BAR() do { asm volatile("s_waitcnt lgkmcnt(0)" ::: "memory"); \
                        __builtin_amdgcn_s_barrier(); } while (0)

// one tile: consume bank c0..c7 (loaded a full tile ago), prefetch n0..n7 from PNEXT
#define GEMM_TILE(TCUR, PNEXT, c0,c1,c2,c3,c4,c5,c6,c7, n0,n1,n2,n3,n4,n5,n6,n7)   \
  {                                                                                 \
    f32x16 acc0 = {}, acc1 = {};                                                    \
    const long long r0 = (TCUR) * 64;                                               \
    gemm_cvt_write(c0, c1, As0, aws0, aws1);                                        \
    n0 = *(const float4*)(PNEXT);       n1 = *(const float4*)((PNEXT) + 32 * CDIM); \
    GEMM_BAR();                                                                     \
    gemm_mfma_step(As0, Bs, rA, hi16, nB0, nB1, 0, acc0, acc1);                     \
    gemm_cvt_write(c2, c3, As1, aws0, aws1);                                        \
    n2 = *(const float4*)((PNEXT) + 64); n3 = *(const float4*)((PNEXT) + 64 + 32 * CDIM); \
    GEMM_BAR();                                                                     \
    gemm_mfma_step(As1, Bs, rA, hi16, nB0, nB1, 128, acc0, acc1);                   \
    gemm_cvt_write(c4, c5, As0, aws0, aws1);                                        \
    n4 = *(const float4*)((PNEXT) + 128); n5 = *(const float4*)((PNEXT) + 128 + 32 * CDIM); \
    GEMM_BAR();                                                                     \
    gemm_mfma_step(As0, Bs, rA, hi16, nB0, nB1, 256, acc0, acc1);                   \
    gemm_cvt_write(c6, c7, As1, aws0, aws1);                                        \
    n6 = *(const float4*)((PNEXT) + 192); n7 = *(const float4*)((PNEXT) + 192 + 32 * CDIM); \
    GEMM_BAR();                                                                     \
    gemm_mfma_step(As1, Bs, rA, hi16, nB0, nB1, 384, acc0, acc1);                   \
    const int sg0 = seg_of(r0, off, is64);                                          \
    const bool uni = g0 || (sg0 == seg_of(r0 + 63, off, is64));                     \
    const float* bsrc = g0 ? bo : (bias + sg0 * CDIM);                              \
    const int col0 = wx * 64 + (lane & 31);                                         \
    const int col1 = col0 + 32;                                                     \
    const float bvu0 = bsrc[col0];                                                  \
    const float bvu1 = bsrc[col1];                                                  \
    _Pragma("unroll")                                                               \
    for (int reg = 0; reg < 16; ++reg) {                                            \
      const int rin = wy * 32 + 4 * (lane >> 5) + (reg & 3) + 8 * (reg >> 2);       \
      const long long grow = r0 + rin;                                              \
      float bb0 = bvu0, bb1 = bvu1;                                                 \
      if (!uni) {                                                                   \
        const int sg = seg_of(grow, off, is64);                                     \
        bb0 = bias[sg * CDIM + col0];                                               \
        bb1 = bias[sg * CDIM + col1];                                               \
      }                                                                             \
      __builtin_nontemporal_store(acc0[reg] + bb0, &out[grow * CDIM + col0]);       \
      __builtin_nontemporal_store(acc1[reg] + bb1, &out[grow * CDIM + col1]);       \
    }                                                                               \
  }

// ---------------- K5: out = xa @ Wo + bias[seg] ----------------
// 256 blocks x 512 thr (8 waves, wave grid 2x4, wave tile 32 rows x 64 cols).
// B (wot bf16, 128 KB) staged once into persistent swizzled LDS (writes at b128 bank floor).
// A: full-tile register prefetch (two 8-slot banks), lgkm-only barriers.
// Nontemporal stores for out. bias source = bo when gamma==0 (no biasv dependency).
__global__ __launch_bounds__(512, 2) void k_gemm(const float* __restrict__ xa,
                                                 const unsigned short* __restrict__ wot,
                                                 const float* __restrict__ bias,
                                                 const float* __restrict__ bo,
                                                 const float* __restrict__ gamma,
                                                 const int* __restrict__ off,
                                                 float* __restrict__ out) {
  extern __shared__ char smem[];
  unsigned short* Bs  = (unsigned short*)smem;                    // 131072 B
  unsigned short* As0 = (unsigned short*)(smem + 131072);         // 8192 B
  unsigned short* As1 = (unsigned short*)(smem + 131072 + 8192);  // 8192 B

  const int t = threadIdx.x, lane = t & 63, w = t >> 6;
  const int wy = w >> 2, wx = w & 3;          // wave grid 2 x 4
  const bool is64 = off_is64(off);
  const bool g0 = (*gamma == 0.0f);

  // A staging: thread covers rows arow0 (lo) and arow0+32 (hi), float4 chunk ac
  const int arow0 = t >> 4;                   // 0..31
  const int ac = t & 15;                      // 16B chunk within 64-k row
  const int arow1 = arow0 + 32;
  const int aws0 = arow0 * 128 + ((ac * 8) ^ ((arow0 & 7) << 4));
  const int aws1 = arow1 * 128 + ((ac * 8) ^ ((arow1 & 7) << 4));

  // prologue: fully load bank A = tile blockIdx.x (8 float4, in flight during B staging)
  float4 a0, a1, a2, a3, a4, a5, a6, a7;      // bank A (current tile at loop entry)
  float4 b0, b1, b2, b3, b4, b5, b6, b7;      // bank B (next tile, filled during compute)
  {
    const float* p = xa + ((long long)blockIdx.x * 64 + arow0) * CDIM + ac * 4;
    a0 = *(const float4*)(p);        a1 = *(const float4*)(p + 32 * CDIM);
    a2 = *(const float4*)(p + 64);   a3 = *(const float4*)(p + 64 + 32 * CDIM);
    a4 = *(const float4*)(p + 128);  a5 = *(const float4*)(p + 128 + 32 * CDIM);
    a6 = *(const float4*)(p + 192);  a7 = *(const float4*)(p + 192 + 32 * CDIM);
  }

  // stage B once: wot[n][k] bf16 -> Bs swizzled (coalesced reads, writes at b128 bank floor)
  #pragma unroll
  for (int pp = 0; pp < 16; ++pp) {
    int q = t + pp * 512;
    int n = q >> 5, c = q & 31;
    uint4 u = *(const uint4*)(wot + n * CDIM + c * 8);
    int d = n * 512 + ((c * 16) ^ ((n & 31) << 4));
    *(uint4*)((char*)Bs + d) = u;
  }
  __syncthreads();

  // per-wave MFMA read coordinates
  const int rA = wy * 32 + (lane & 31);
  const int hi16 = (lane >> 5) * 16;
  const int nB0 = wx * 64 + (lane & 31);
  const int nB1 = nB0 + 32;

  long long tile = blockIdx.x;
  #pragma unroll 1
  for (int it = 0; it < 8; ++it) {
    // tile T0 = tile (bank a), prefetch T1 = tile+256 into bank b  [T1 < 4096 always]
    const float* pn1 = xa + ((tile + GEMM_BLOCKS) * 64 + arow0) * CDIM + ac * 4;
    GEMM_TILE(tile, pn1, a0, a1, a2, a3, a4, a5, a6, a7,
                         b0, b1, b2, b3, b4, b5, b6, b7);
    // tile T1 (bank b), prefetch T2 = tile+512 into bank a (clamped on last iter)
    const long long t2 = tile + 2 * GEMM_BLOCKS;
    const float* pn2 = xa + (((t2 < GEMM_NT) ? t2 : tile) * 64 + arow0) * CDIM + ac * 4;
    GEMM_TILE(tile + GEMM_BLOCKS, pn2, b0, b1, b2, b3, b4, b5, b6, b7,
                                       a0, a1, a2, a3, a4, a5, a6, a7);
    tile += 2 * GEMM_BLOCKS;
  }
}

extern "C" void kernel_launch(void* const* d_in, const int* in_sizes, int n_in,
                              void* d_out, int out_size, void* d_ws, size_t ws_size,
                              hipStream_t stream) {
  const float* xa    = (const float*)d_in[0];
  const float* xb    = (const float*)d_in[1];
  const int*   off   = (const int*)d_in[2];
  const float* Wq    = (const float*)d_in[3];
  const float* Wk    = (const float*)d_in[4];
  const float* Wv    = (const float*)d_in[5];
  const float* Wp    = (const float*)d_in[6];
  const float* bp    = (const float*)d_in[7];
  const float* Wr1   = (const float*)d_in[8];
  const float* br1   = (const float*)d_in[9];
  const float* Wr2   = (const float*)d_in[10];
  const float* br2   = (const float*)d_in[11];
  const float* gamma = (const float*)d_in[12];
  const float* Wo    = (const float*)d_in[13];
  const float* bo    = (const float*)d_in[14];
  float* out = (float*)d_out;

  float* ws = (float*)d_ws;
  float* S_atomic   = ws + 0;        // 32768
  float* cls_atomic = ws + 32768;    // 4096
  float* denom_at   = ws + 36864;    // 128   (zero region [0,36992))
  float* Kq         = ws + 69888;    // 32768
  float* biasv      = ws + 102656;   // 4096
  unsigned short* wot = (unsigned short*)(ws + 106752); // 65536 bf16 (32768 floats)
  int*   tags_s     = (int*)(ws + 139520);   // 2048
  int*   taga       = (int*)(ws + 141568);   // 2048
  float* Dpart      = ws + 143616;   // 16384
  float* Apart      = ws + 160000;   // 524288
  float* Spart      = ws + 684288;   // 4194304
  const size_t needed = (size_t)(684288 + 4194304) * 4;   // ~19.5 MB
  const int use_slots = (ws_size >= needed) ? 1 : 0;

  hipMemsetAsync(ws, 0, 36992 * sizeof(float), stream);

  k_wotseg<<<256 + NB, 256, 0, stream>>>(Wo, wot, xa, off, Apart, taga, cls_atomic, gamma, use_slots);
  k_prep  <<<16,  256, 0, stream>>>(Apart, taga, cls_atomic, off, Wq, Wk, Kq, gamma, use_slots ? NB : 0);
  k_stats <<<NB,  256, 0, stream>>>(xb, off, Kq, Spart, Dpart, tags_s, S_atomic, denom_at, gamma, use_slots);
  k_post  <<<16,  256, 0, stream>>>(Spart, Dpart, tags_s, S_atomic, denom_at, off, Wv, Wp, bp,
                                    Wr1, br1, Wr2, br2, gamma, Wo, bo, biasv, use_slots ? NB : 0);
  k_gemm  <<<GEMM_BLOCKS, 512, 147456, stream>>>(xa, wot, biasv, bo, gamma, off, out);
}

// Round 12
// 104.510 us; speedup vs baseline: 9.1229x; 1.0050x over previous
//
#include <hip/hip_runtime.h>

// CrossViTPointFusion: N=262144 pts, B=16 segs, C=256, H=8, Dh=32.
// out = x_a @ Wo + bias[seg]; bias = bo + gamma*(cls_proj@Wo) (distributivity).
// Attention folded: logits = x_b . Kq[seg]; S = sum p*x_b; softmax shift-invariance => m=0 exact.
// Round 11: REVERT to round-9 kernel (best: 104.7 us). Round-10's barrier-free variant
// falsified: nt partial-line writes without barrier-synced bursts -> RMW amplification
// (WRITE 10x, FETCH 4x). r9 = wot-staged LDS B, full-tile register prefetch, lgkm-only
// barriers, nt stores, bo-direct gamma==0 path. 6 dispatches.

#define NPTS 262144
#define NSEG 16
#define CDIM 256
#define HNUM 8
#define DH   32
#define NB   2048      // blocks for segsum/stats

#define GEMM_BLOCKS 256
#define GEMM_NT     4096     // 262144 / 64 rows per tile

using bf16x8 = __attribute__((ext_vector_type(8))) __bf16;
using f32x16 = __attribute__((ext_vector_type(16))) float;

__device__ __forceinline__ unsigned short f2bf(float f) {
  unsigned int u = __float_as_uint(f);
  unsigned int r = u + 0x7FFFu + ((u >> 16) & 1u);   // RNE, inputs finite
  return (unsigned short)(r >> 16);
}

// offsets: reference declares int64 but JAX without x64 yields int32. Sniff word 1.
__device__ __forceinline__ bool off_is64(const int* o) { return o[1] == 0; }
__device__ __forceinline__ long long off_at(const int* o, int i, bool is64) {
  return is64 ? ((const long long*)o)[i] : (long long)o[i];
}
__device__ __forceinline__ int seg_of(long long row, const int* o, bool is64) {
  int s = 0;
  while (s < NSEG - 1 && row >= off_at(o, s, is64)) ++s;
  return s;
}

// DPP rotate-add. CTRL: 0xB1 quad xor1, 0x4E quad xor2, 0x124 row_ror:4, 0x128 row_ror:8.
template <int CTRL>
__device__ __forceinline__ float dpp_add(float x) {
  int m = __builtin_amdgcn_update_dpp(0, __float_as_int(x), CTRL, 0xF, 0xF, true);
  return x + __int_as_float(m);
}

__device__ __forceinline__ void allred8(float lp[8]) {
  #pragma unroll
  for (int h = 0; h < 8; ++h) {
    float s = lp[h];
    s = dpp_add<0xB1>(s);
    s = dpp_add<0x4E>(s);
    s = dpp_add<0x124>(s);
    s = dpp_add<0x128>(s);
    s += __shfl_xor(s, 16, 64);
    s += __shfl_xor(s, 32, 64);
    lp[h] = s;
  }
}

// ---------------- K1: Wo^T bf16 (blocks 0..255) + per-segment column sums of x_a ----------------
__global__ __launch_bounds__(256) void k_wotseg(const float* __restrict__ Wo,
                                                unsigned short* __restrict__ wotp,
                                                const float* __restrict__ xa,
                                                const int* __restrict__ off,
                                                float* __restrict__ Apart,
                                                int* __restrict__ taga,
                                                float* __restrict__ cls_atomic,
                                                const float* __restrict__ gamma,
                                                int use_slots) {
  if (blockIdx.x < 256) {
    const int o = blockIdx.x * 256 + threadIdx.x;   // 65536; o = k*256+n (coalesced read)
    const int k = o >> 8, n = o & 255;
    wotp[n * CDIM + k] = f2bf(Wo[o]);
    return;
  }
  if (*gamma == 0.0f) return;     // attention path contributes gamma * (...) == 0 exactly
  const int bid = blockIdx.x - 256;
  const bool is64 = off_is64(off);
  const int t = threadIdx.x, lane = t & 63, w = t >> 6;
  const long long r0b = (long long)bid * 128;
  const int sg0 = seg_of(r0b, off, is64), sg1 = seg_of(r0b + 127, off, is64);
  const long long rw0 = r0b + (long long)w * 32;
  __shared__ float red[4][256];

  if (use_slots && sg0 == sg1) {
    float acc[4] = {0.f, 0.f, 0.f, 0.f};
    for (int r = 0; r < 32; ++r) {
      float4 xv = *(const float4*)&xa[(rw0 + r) * CDIM + lane * 4];
      acc[0] += xv.x; acc[1] += xv.y; acc[2] += xv.z; acc[3] += xv.w;
    }
    *(float4*)&red[w][lane * 4] = make_float4(acc[0], acc[1], acc[2], acc[3]);
    __syncthreads();
    Apart[bid * 256 + t] = red[0][t] + red[1][t] + red[2][t] + red[3][t];
    if (t == 0) taga[bid] = sg0;
  } else {
    int sg = seg_of(rw0, off, is64);
    long long segend = off_at(off, sg, is64);
    float acc[4] = {0.f, 0.f, 0.f, 0.f};
    for (int r = 0; r < 32; ++r) {
      long long row = rw0 + r;
      if (row >= segend) {
        #pragma unroll
        for (int i = 0; i < 4; ++i) { atomicAdd(&cls_atomic[sg * CDIM + lane * 4 + i], acc[i]); acc[i] = 0.f; }
        sg = seg_of(row, off, is64);
        segend = off_at(off, sg, is64);
      }
      float4 xv = *(const float4*)&xa[row * CDIM + lane * 4];
      acc[0] += xv.x; acc[1] += xv.y; acc[2] += xv.z; acc[3] += xv.w;
    }
    #pragma unroll
    for (int i = 0; i < 4; ++i) atomicAdd(&cls_atomic[sg * CDIM + lane * 4 + i], acc[i]);
    if (use_slots) {
      Apart[bid * 256 + t] = 0.f;
      if (t == 0) taga[bid] = -1;
    }
  }
}

// ---------------- K2: fused cls-reduce + q + Kq (16 blocks) ----------------
__global__ __launch_bounds__(256) void k_prep(const float* __restrict__ Apart,
                                              const int* __restrict__ taga,
                                              const float* __restrict__ cls_atomic,
                                              const int* __restrict__ off,
                                              const float* __restrict__ Wq,
                                              const float* __restrict__ Wk,
                                              float* __restrict__ Kq,
                                              const float* __restrict__ gamma,
                                              int nb) {
  if (*gamma == 0.0f) return;
  const int b = blockIdx.x, t = threadIdx.x;
  const bool is64 = off_is64(off);
  __shared__ float cls[256], qv[256];
  long long lo = b ? off_at(off, b - 1, is64) : 0;
  long long hi = off_at(off, b, is64);
  float s = cls_atomic[b * CDIM + t];
  if (nb > 0) {
    int wlo = (int)(lo / 128); if (wlo < 0) wlo = 0;
    int whi = (int)((hi + 127) / 128); if (whi > nb) whi = nb;
    for (int w = wlo; w < whi; ++w)
      if (taga[w] == b) s += Apart[w * 256 + t];
  }
  cls[t] = s;
  __syncthreads();
  long long cnt = hi - lo; if (cnt < 1) cnt = 1;
  float inv = 1.0f / (float)cnt;
  float qs = 0.f;
  for (int c = 0; c < CDIM; ++c) qs += cls[c] * Wq[c * CDIM + t];
  qv[t] = qs * inv;
  __syncthreads();
  const float scale = 0.17677669529663687f;
  #pragma unroll
  for (int h = 0; h < HNUM; ++h) {
    float kk = 0.f;
    #pragma unroll 8
    for (int d = 0; d < DH; ++d) kk += Wk[t * CDIM + h * DH + d] * qv[h * DH + d];
    Kq[(b * HNUM + h) * CDIM + t] = kk * scale;
  }
}

// ---------------- K3: fused stats pass over x_b -> per-block slots ----------------
__global__ __launch_bounds__(256) void k_stats(const float* __restrict__ xb,
                                               const int* __restrict__ off,
                                               const float* __restrict__ Kq,
                                               float* __restrict__ Spart,
                                               float* __restrict__ Dpart,
                                               int* __restrict__ tags,
                                               float* __restrict__ S_atomic,
                                               float* __restrict__ denom_atomic,
                                               const float* __restrict__ gamma,
                                               int use_slots) {
  if (*gamma == 0.0f) return;
  const bool is64 = off_is64(off);
  const int t = threadIdx.x, lane = t & 63, w = t >> 6;
  const long long r0b = (long long)blockIdx.x * 128;
  const int sg0 = seg_of(r0b, off, is64), sg1 = seg_of(r0b + 127, off, is64);
  const long long rw0 = r0b + (long long)w * 32;
  __shared__ float red[4][2048];
  __shared__ float dred[4][8];

  if (use_slots && sg0 == sg1) {
    float kq[8][4];
    #pragma unroll
    for (int h = 0; h < 8; ++h) {
      float4 v = *(const float4*)&Kq[(sg0 * 8 + h) * CDIM + lane * 4];
      kq[h][0] = v.x; kq[h][1] = v.y; kq[h][2] = v.z; kq[h][3] = v.w;
    }
    float sacc[8][4]; float dacc[8];
    #pragma unroll
    for (int h = 0; h < 8; ++h) { dacc[h] = 0.f; sacc[h][0]=sacc[h][1]=sacc[h][2]=sacc[h][3]=0.f; }

    #pragma unroll 2
    for (int r = 0; r < 32; ++r) {
      float4 xv = *(const float4*)&xb[(rw0 + r) * CDIM + lane * 4];
      float lp[8];
      #pragma unroll
      for (int h = 0; h < 8; ++h)
        lp[h] = xv.x*kq[h][0] + xv.y*kq[h][1] + xv.z*kq[h][2] + xv.w*kq[h][3];
      allred8(lp);
      #pragma unroll
      for (int h = 0; h < 8; ++h) {
        float p = __expf(lp[h]);
        dacc[h] += p;
        sacc[h][0] += p*xv.x; sacc[h][1] += p*xv.y; sacc[h][2] += p*xv.z; sacc[h][3] += p*xv.w;
      }
    }
    #pragma unroll
    for (int h = 0; h < 8; ++h)
      *(float4*)&red[w][h * 256 + lane * 4] = make_float4(sacc[h][0], sacc[h][1], sacc[h][2], sacc[h][3]);
    if (lane == 0) {
      #pragma unroll
      for (int h = 0; h < 8; ++h) dred[w][h] = dacc[h];
    }
    __syncthreads();
    #pragma unroll
    for (int k = 0; k < 8; ++k) {
      int e = k * 256 + t;
      Spart[(long long)blockIdx.x * 2048 + e] = red[0][e] + red[1][e] + red[2][e] + red[3][e];
    }
    if (t < 8) Dpart[blockIdx.x * 8 + t] = dred[0][t] + dred[1][t] + dred[2][t] + dred[3][t];
    if (t == 0) tags[blockIdx.x] = sg0;
  } else {
    int sg = seg_of(rw0, off, is64);
    long long segend = off_at(off, sg, is64);
    float kq[8][4];
    #pragma unroll
    for (int h = 0; h < 8; ++h) {
      float4 v = *(const float4*)&Kq[(sg * 8 + h) * CDIM + lane * 4];
      kq[h][0] = v.x; kq[h][1] = v.y; kq[h][2] = v.z; kq[h][3] = v.w;
    }
    float sacc[8][4]; float dacc[8];
    #pragma unroll
    for (int h = 0; h < 8; ++h) { dacc[h] = 0.f; sacc[h][0]=sacc[h][1]=sacc[h][2]=sacc[h][3]=0.f; }
    for (int r = 0; r < 32; ++r) {
      long long row = rw0 + r;
      if (row >= segend) {
        #pragma unroll
        for (int h = 0; h < 8; ++h) {
          #pragma unroll
          for (int i = 0; i < 4; ++i) { atomicAdd(&S_atomic[(sg*8+h)*CDIM + lane*4 + i], sacc[h][i]); sacc[h][i]=0.f; }
          if (lane == 0) atomicAdd(&denom_atomic[sg*8+h], dacc[h]);
          dacc[h] = 0.f;
        }
        sg = seg_of(row, off, is64);
        segend = off_at(off, sg, is64);
        #pragma unroll
        for (int h = 0; h < 8; ++h) {
          float4 v = *(const float4*)&Kq[(sg * 8 + h) * CDIM + lane * 4];
          kq[h][0] = v.x; kq[h][1] = v.y; kq[h][2] = v.z; kq[h][3] = v.w;
        }
      }
      float4 xv = *(const float4*)&xb[row * CDIM + lane * 4];
      float lp[8];
      #pragma unroll
      for (int h = 0; h < 8; ++h)
        lp[h] = xv.x*kq[h][0] + xv.y*kq[h][1] + xv.z*kq[h][2] + xv.w*kq[h][3];
      allred8(lp);
      #pragma unroll
      for (int h = 0; h < 8; ++h) {
        float p = __expf(lp[h]);
        dacc[h] += p;
        sacc[h][0] += p*xv.x; sacc[h][1] += p*xv.y; sacc[h][2] += p*xv.z; sacc[h][3] += p*xv.w;
      }
    }
    #pragma unroll
    for (int h = 0; h < 8; ++h) {
      #pragma unroll
      for (int i = 0; i < 4; ++i) atomicAdd(&S_atomic[(sg*8+h)*CDIM + lane*4 + i], sacc[h][i]);
      if (lane == 0) atomicAdd(&denom_atomic[sg*8+h], dacc[h]);
    }
    if (use_slots) {
      #pragma unroll
      for (int k = 0; k < 8; ++k) Spart[(long long)blockIdx.x * 2048 + k * 256 + t] = 0.f;
      if (t < 8) Dpart[blockIdx.x * 8 + t] = 0.f;
      if (t == 0) tags[blockIdx.x] = -1;
    }
  }
}

// ---------------- K4: slot-reduce + out_cls + MLP chain + biasv (16 blocks) ----------------
__global__ __launch_bounds__(256) void k_post(const float* __restrict__ Spart,
                                              const float* __restrict__ Dpart,
                                              const int* __restrict__ tags,
                                              const float* __restrict__ S_atomic,
                                              const float* __restrict__ denom_atomic,
                                              const int* __restrict__ off,
                                              const float* __restrict__ Wv,
                                              const float* __restrict__ Wp, const float* __restrict__ bp,
                                              const float* __restrict__ Wr1, const float* __restrict__ br1,
                                              const float* __restrict__ Wr2, const float* __restrict__ br2,
                                              const float* __restrict__ gamma,
                                              const float* __restrict__ Wo, const float* __restrict__ bo,
                                              float* __restrict__ biasv,
                                              int nb) {
  const int b = blockIdx.x, t = threadIdx.x;
  const float g = *gamma;
  if (g == 0.0f) return;          // k_gemm sources bo directly when gamma==0
  const bool is64 = off_is64(off);
  __shared__ float sb[8][256];
  __shared__ float db[8];
  __shared__ float v0[256], v1[256];
  long long lo = b ? off_at(off, b - 1, is64) : 0;
  long long hi = off_at(off, b, is64);
  int wlo = (int)(lo / 128); if (wlo < 0) wlo = 0;
  int whi = (int)((hi + 127) / 128); if (whi > nb) whi = nb;
  #pragma unroll
  for (int k = 0; k < 8; ++k) {
    const int e = k * 256 + t;
    float s = S_atomic[b * 2048 + e];
    for (int w = wlo; w < whi; ++w)
      if (tags[w] == b) s += Spart[(long long)w * 2048 + e];
    sb[k][t] = s;
  }
  if (t < 8) {
    float d = denom_atomic[b * 8 + t];
    for (int w = wlo; w < whi; ++w)
      if (tags[w] == b) d += Dpart[w * 8 + t];
    db[t] = d;
  }
  __syncthreads();
  const int h = t >> 5;
  float oc = 0.f;
  for (int c = 0; c < CDIM; ++c) oc += Wv[c * CDIM + t] * sb[h][c];
  oc /= db[h];
  v0[t] = oc;
  __syncthreads();
  float a = bp[t];
  for (int c = 0; c < CDIM; ++c) a += v0[c] * Wp[c * CDIM + t];
  v1[t] = a;
  __syncthreads();
  float r1 = br1[t];
  for (int c = 0; c < CDIM; ++c) r1 += v1[c] * Wr1[c * CDIM + t];
  r1 = fmaxf(r1, 0.f);
  v0[t] = r1;
  __syncthreads();
  float r2 = br2[t];
  for (int c = 0; c < CDIM; ++c) r2 += v0[c] * Wr2[c * CDIM + t];
  v1[t] = r2;
  __syncthreads();
  float acc = 0.f;
  for (int c = 0; c < CDIM; ++c) acc += v1[c] * Wo[c * CDIM + t];
  biasv[b * CDIM + t] = bo[t] + g * acc;
}

// ---------------- K5 helpers ----------------
__device__ __forceinline__ void gemm_mfma_step(const unsigned short* Abuf,
                                               const unsigned short* Bs,
                                               int rA, int hi16, int nB0, int nB1, int sbyte,
                                               f32x16& acc0, f32x16& acc1) {
  #pragma unroll
  for (int ks = 0; ks < 4; ++ks) {
    const bf16x8 a = *(const bf16x8*)((const char*)Abuf + rA * 128 +
                       ((ks * 32 + hi16) ^ ((rA & 7) << 4)));
    const bf16x8 b0 = *(const bf16x8*)((const char*)Bs + nB0 * 512 +
                       ((sbyte + ks * 32 + hi16) ^ ((nB0 & 31) << 4)));
    const bf16x8 b1 = *(const bf16x8*)((const char*)Bs + nB1 * 512 +
                       ((sbyte + ks * 32 + hi16) ^ ((nB1 & 31) << 4)));
    acc0 = __builtin_amdgcn_mfma_f32_32x32x16_bf16(a, b0, acc0, 0, 0, 0);
    acc1 = __builtin_amdgcn_mfma_f32_32x32x16_bf16(a, b1, acc1, 0, 0, 0);
  }
}

__device__ __forceinline__ void gemm_cvt_write(const float4& sa, const float4& sb,
                                               unsigned short* Abuf, int aws0, int aws1) {
  unsigned int u0 = (unsigned int)f2bf(sa.x) | ((unsigned int)f2bf(sa.y) << 16);
  unsigned int u1 = (unsigned int)f2bf(sa.z) | ((unsigned int)f2bf(sa.w) << 16);
  unsigned int u2 = (unsigned int)f2bf(sb.x) | ((unsigned int)f2bf(sb.y) << 16);
  unsigned int u3 = (unsigned int)f2bf(sb.z) | ((unsigned int)f2bf(sb.w) << 16);
  uint2 w0; w0.x = u0; w0.y = u1;
  uint2 w1; w1.x = u2; w1.y = u3;
  *(uint2*)((char*)Abuf + aws0) = w0;
  *(uint2*)((char*)Abuf + aws1) = w1;
}

#define GEMM_BAR() do { asm volatile("s_waitcnt lgkmcnt(0)" ::: "memory"); \
                        __builtin_amdgcn_s_barrier(); } while (0)

// one tile: consume bank c0..c7 (loaded a full tile ago), prefetch n0..n7 from PNEXT
#define GEMM_TILE(TCUR, PNEXT, c0,c1,c2,c3,c4,c5,c6,c7, n0,n1,n2,n3,n4,n5,n6,n7)   \
  {                                                                                 \
    f32x16 acc0 = {}, acc1 = {};                                                    \
    const long long r0 = (TCUR) * 64;                                               \
    gemm_cvt_write(c0, c1, As0, aws0, aws1);                                        \
    n0 = *(const float4*)(PNEXT);       n1 = *(const float4*)((PNEXT) + 32 * CDIM); \
    GEMM_BAR();                                                                     \
    gemm_mfma_step(As0, Bs, rA, hi16, nB0, nB1, 0, acc0, acc1);                     \
    gemm_cvt_write(c2, c3, As1, aws0, aws1);                                        \
    n2 = *(const float4*)((PNEXT) + 64); n3 = *(const float4*)((PNEXT) + 64 + 32 * CDIM); \
    GEMM_BAR();                                                                     \
    gemm_mfma_step(As1, Bs, rA, hi16, nB0, nB1, 128, acc0, acc1);                   \
    gemm_cvt_write(c4, c5, As0, aws0, aws1);                                        \
    n4 = *(const float4*)((PNEXT) + 128); n5 = *(const float4*)((PNEXT) + 128 + 32 * CDIM); \
    GEMM_BAR();                                                                     \
    gemm_mfma_step(As0, Bs, rA, hi16, nB0, nB1, 256, acc0, acc1);                   \
    gemm_cvt_write(c6, c7, As1, aws0, aws1);                                        \
    n6 = *(const float4*)((PNEXT) + 192); n7 = *(const float4*)((PNEXT) + 192 + 32 * CDIM); \
    GEMM_BAR();                                                                     \
    gemm_mfma_step(As1, Bs, rA, hi16, nB0, nB1, 384, acc0, acc1);                   \
    const int sg0 = seg_of(r0, off, is64);                                          \
    const bool uni = g0 || (sg0 == seg_of(r0 + 63, off, is64));                     \
    const float* bsrc = g0 ? bo : (bias + sg0 * CDIM);                              \
    const int col0 = wx * 64 + (lane & 31);                                         \
    const int col1 = col0 + 32;                                                     \
    const float bvu0 = bsrc[col0];                                                  \
    const float bvu1 = bsrc[col1];                                                  \
    _Pragma("unroll")                                                               \
    for (int reg = 0; reg < 16; ++reg) {                                            \
      const int rin = wy * 32 + 4 * (lane >> 5) + (reg & 3) + 8 * (reg >> 2);       \
      const long long grow = r0 + rin;                                              \
      float bb0 = bvu0, bb1 = bvu1;                                                 \
      if (!uni) {                                                                   \
        const int sg = seg_of(grow, off, is64);                                     \
        bb0 = bias[sg * CDIM + col0];                                               \
        bb1 = bias[sg * CDIM + col1];                                               \
      }                                                                             \
      __builtin_nontemporal_store(acc0[reg] + bb0, &out[grow * CDIM + col0]);       \
      __builtin_nontemporal_store(acc1[reg] + bb1, &out[grow * CDIM + col1]);       \
    }                                                                               \
  }

// ---------------- K5: out = xa @ Wo + bias[seg] ----------------
// 256 blocks x 512 thr (8 waves, wave grid 2x4, wave tile 32 rows x 64 cols).
// B (wot bf16, 128 KB) staged once into persistent swizzled LDS (writes at b128 bank floor).
// A: full-tile register prefetch (two 8-slot banks), lgkm-only barriers.
// Nontemporal stores for out. bias source = bo when gamma==0 (no biasv dependency).
__global__ __launch_bounds__(512, 2) void k_gemm(const float* __restrict__ xa,
                                                 const unsigned short* __restrict__ wot,
                                                 const float* __restrict__ bias,
                                                 const float* __restrict__ bo,
                                                 const float* __restrict__ gamma,
                                                 const int* __restrict__ off,
                                                 float* __restrict__ out) {
  extern __shared__ char smem[];
  unsigned short* Bs  = (unsigned short*)smem;                    // 131072 B
  unsigned short* As0 = (unsigned short*)(smem + 131072);         // 8192 B
  unsigned short* As1 = (unsigned short*)(smem + 131072 + 8192);  // 8192 B

  const int t = threadIdx.x, lane = t & 63, w = t >> 6;
  const int wy = w >> 2, wx = w & 3;          // wave grid 2 x 4
  const bool is64 = off_is64(off);
  const bool g0 = (*gamma == 0.0f);

  // A staging: thread covers rows arow0 (lo) and arow0+32 (hi), float4 chunk ac
  const int arow0 = t >> 4;                   // 0..31
  const int ac = t & 15;                      // 16B chunk within 64-k row
  const int arow1 = arow0 + 32;
  const int aws0 = arow0 * 128 + ((ac * 8) ^ ((arow0 & 7) << 4));
  const int aws1 = arow1 * 128 + ((ac * 8) ^ ((arow1 & 7) << 4));

  // prologue: fully load bank A = tile blockIdx.x (8 float4, in flight during B staging)
  float4 a0, a1, a2, a3, a4, a5, a6, a7;      // bank A (current tile at loop entry)
  float4 b0, b1, b2, b3, b4, b5, b6, b7;      // bank B (next tile, filled during compute)
  {
    const float* p = xa + ((long long)blockIdx.x * 64 + arow0) * CDIM + ac * 4;
    a0 = *(const float4*)(p);        a1 = *(const float4*)(p + 32 * CDIM);
    a2 = *(const float4*)(p + 64);   a3 = *(const float4*)(p + 64 + 32 * CDIM);
    a4 = *(const float4*)(p + 128);  a5 = *(const float4*)(p + 128 + 32 * CDIM);
    a6 = *(const float4*)(p + 192);  a7 = *(const float4*)(p + 192 + 32 * CDIM);
  }

  // stage B once: wot[n][k] bf16 -> Bs swizzled (coalesced reads, writes at b128 bank floor)
  #pragma unroll
  for (int pp = 0; pp < 16; ++pp) {
    int q = t + pp * 512;
    int n = q >> 5, c = q & 31;
    uint4 u = *(const uint4*)(wot + n * CDIM + c * 8);
    int d = n * 512 + ((c * 16) ^ ((n & 31) << 4));
    *(uint4*)((char*)Bs + d) = u;
  }
  __syncthreads();

  // per-wave MFMA read coordinates
  const int rA = wy * 32 + (lane & 31);
  const int hi16 = (lane >> 5) * 16;
  const int nB0 = wx * 64 + (lane & 31);
  const int nB1 = nB0 + 32;

  long long tile = blockIdx.x;
  #pragma unroll 1
  for (int it = 0; it < 8; ++it) {
    // tile T0 = tile (bank a), prefetch T1 = tile+256 into bank b  [T1 < 4096 always]
    const float* pn1 = xa + ((tile + GEMM_BLOCKS) * 64 + arow0) * CDIM + ac * 4;
    GEMM_TILE(tile, pn1, a0, a1, a2, a3, a4, a5, a6, a7,
                         b0, b1, b2, b3, b4, b5, b6, b7);
    // tile T1 (bank b), prefetch T2 = tile+512 into bank a (clamped on last iter)
    const long long t2 = tile + 2 * GEMM_BLOCKS;
    const float* pn2 = xa + (((t2 < GEMM_NT) ? t2 : tile) * 64 + arow0) * CDIM + ac * 4;
    GEMM_TILE(tile + GEMM_BLOCKS, pn2, b0, b1, b2, b3, b4, b5, b6, b7,
                                       a0, a1, a2, a3, a4, a5, a6, a7);
    tile += 2 * GEMM_BLOCKS;
  }
}

extern "C" void kernel_launch(void* const* d_in, const int* in_sizes, int n_in,
                              void* d_out, int out_size, void* d_ws, size_t ws_size,
                              hipStream_t stream) {
  const float* xa    = (const float*)d_in[0];
  const float* xb    = (const float*)d_in[1];
  const int*   off   = (const int*)d_in[2];
  const float* Wq    = (const float*)d_in[3];
  const float* Wk    = (const float*)d_in[4];
  const float* Wv    = (const float*)d_in[5];
  const float* Wp    = (const float*)d_in[6];
  const float* bp    = (const float*)d_in[7];
  const float* Wr1   = (const float*)d_in[8];
  const float* br1   = (const float*)d_in[9];
  const float* Wr2   = (const float*)d_in[10];
  const float* br2   = (const float*)d_in[11];
  const float* gamma = (const float*)d_in[12];
  const float* Wo    = (const float*)d_in[13];
  const float* bo    = (const float*)d_in[14];
  float* out = (float*)d_out;

  float* ws = (float*)d_ws;
  float* S_atomic   = ws + 0;        // 32768
  float* cls_atomic = ws + 32768;    // 4096
  float* denom_at   = ws + 36864;    // 128   (zero region [0,36992))
  float* Kq         = ws + 69888;    // 32768
  float* biasv      = ws + 102656;   // 4096
  unsigned short* wot = (unsigned short*)(ws + 106752); // 65536 bf16 (32768 floats)
  int*   tags_s     = (int*)(ws + 139520);   // 2048
  int*   taga       = (int*)(ws + 141568);   // 2048
  float* Dpart      = ws + 143616;   // 16384
  float* Apart      = ws + 160000;   // 524288
  float* Spart      = ws + 684288;   // 4194304
  const size_t needed = (size_t)(684288 + 4194304) * 4;   // ~19.5 MB
  const int use_slots = (ws_size >= needed) ? 1 : 0;

  hipMemsetAsync(ws, 0, 36992 * sizeof(float), stream);

  k_wotseg<<<256 + NB, 256, 0, stream>>>(Wo, wot, xa, off, Apart, taga, cls_atomic, gamma, use_slots);
  k_prep  <<<16,  256, 0, stream>>>(Apart, taga, cls_atomic, off, Wq, Wk, Kq, gamma, use_slots ? NB : 0);
  k_stats <<<NB,  256, 0, stream>>>(xb, off, Kq, Spart, Dpart, tags_s, S_atomic, denom_at, gamma, use_slots);
  k_post  <<<16,  256, 0, stream>>>(Spart, Dpart, tags_s, S_atomic, denom_at, off, Wv, Wp, bp,
                                    Wr1, br1, Wr2, br2, gamma, Wo, bo, biasv, use_slots ? NB : 0);
  k_gemm  <<<GEMM_BLOCKS, 512, 147456, stream>>>(xa, wot, biasv, bo, gamma, off, out);
}